// Round 1
// baseline (1960.179 us; speedup 1.0000x reference)
//
#include <hip/hip_runtime.h>
#include <math.h>

#define Bq 256
#define Kn 64
#define Dd 2048
#define Nn 50000
#define Cc 5000
#define NHID 512
#define H2d 256

// ---------------- small utility kernels ----------------

__global__ void k_zero_int(int* __restrict__ p, int n) {
    int i = blockIdx.x * 256 + threadIdx.x;
    if (i < n) p[i] = 0;
}

__global__ void k_count(const int* __restrict__ labels, int* __restrict__ cnt, int n) {
    int i = blockIdx.x * 256 + threadIdx.x;
    if (i < n) atomicAdd(&cnt[labels[i]], 1);
}

__global__ __launch_bounds__(1024) void k_scan(const int* __restrict__ cnt,
                                               int* __restrict__ off,
                                               int* __restrict__ pos, int C) {
    __shared__ int s[1024];
    __shared__ int carry;
    int tid = threadIdx.x;
    if (tid == 0) carry = 0;
    __syncthreads();
    for (int base = 0; base < C; base += 1024) {
        int i = base + tid;
        int v = (i < C) ? cnt[i] : 0;
        s[tid] = v;
        __syncthreads();
        for (int o = 1; o < 1024; o <<= 1) {
            int t = (tid >= o) ? s[tid - o] : 0;
            __syncthreads();
            s[tid] += t;
            __syncthreads();
        }
        int excl = carry + s[tid] - v;
        if (i < C) { off[i] = excl; pos[i] = excl; }
        __syncthreads();
        if (tid == 0) carry += s[1023];
        __syncthreads();
    }
}

__global__ void k_scatter(const int* __restrict__ labels, int* __restrict__ pos,
                          int* __restrict__ rowidx, int n) {
    int i = blockIdx.x * 256 + threadIdx.x;
    if (i < n) {
        int p = atomicAdd(&pos[labels[i]], 1);
        rowidx[p] = i;
    }
}

// ---------------- cluster mean + simm ----------------
// one block per cluster, 256 threads, 8 columns each
__global__ __launch_bounds__(256) void k_meansimm(
    const float* __restrict__ feat, const int* __restrict__ rowidx,
    const int* __restrict__ off, const int* __restrict__ cnt,
    float* __restrict__ clu_mean, float* __restrict__ simm) {
    int c = blockIdx.x;
    int t = threadIdx.x;
    int n = cnt[c], st = off[c];
    float acc[8];
#pragma unroll
    for (int j = 0; j < 8; j++) acc[j] = 0.f;
    for (int r = 0; r < n; r++) {
        const float* row = feat + (size_t)rowidx[st + r] * Dd;
#pragma unroll
        for (int j = 0; j < 8; j++) acc[j] += row[j * 256 + t];
    }
    float sc = 1.f / (float)(n > 1 ? n : 1);
    float ss = 0.f;
    float* outr = clu_mean + (size_t)c * Dd;
#pragma unroll
    for (int j = 0; j < 8; j++) {
        float m = acc[j] * sc;
        outr[j * 256 + t] = m;
        ss += m * m;
    }
    __shared__ float red[256];
    red[t] = ss;
    __syncthreads();
    for (int s2 = 128; s2 > 0; s2 >>= 1) {
        if (t < s2) red[t] += red[t + s2];
        __syncthreads();
    }
    if (t == 0) simm[c] = red[0];
}

// ---------------- per-batch: A = softmax(scale(F F^T)), x = normalize(F) - row0 ----------------
__global__ __launch_bounds__(256) void k_build_ax(
    const float* __restrict__ feat, const float* __restrict__ clu_mean,
    const int* __restrict__ labels, const int* __restrict__ indexes,
    const int* __restrict__ knn, const float* __restrict__ all_pred,
    float* __restrict__ Abuf, float* __restrict__ xbuf) {
    int b = blockIdx.x;
    int tid = threadIdx.x;
    __shared__ float smem[64 * 68];    // F chunk (ld=68); later pivot*rn0 (2048 floats)
    __shared__ float Gs[64 * 65];      // Gram matrix
    __shared__ const float* rowp[64];
    __shared__ float wj[64], rn[64];

    if (tid < 64) {
        int j = tid;
        const float* p;
        if (j == 0) p = feat + (size_t)indexes[b] * Dd;
        else        p = clu_mean + (size_t)labels[knn[b * 64 + j]] * Dd;
        rowp[j] = p;
    }

    int ty = tid >> 4, tx = tid & 15;   // 16x16 threads, 4x4 outputs each
    float acc[4][4];
#pragma unroll
    for (int i = 0; i < 4; i++)
#pragma unroll
        for (int j = 0; j < 4; j++) acc[i][j] = 0.f;

    for (int ch = 0; ch < 32; ch++) {
        int d0 = ch * 64;
        __syncthreads();
#pragma unroll
        for (int kq = 0; kq < 4; kq++) {
            int e4 = tid + kq * 256;
            int row = e4 >> 4;
            int c4 = (e4 & 15) * 4;
            float4 v = *(const float4*)(rowp[row] + d0 + c4);
            *(float4*)&smem[row * 68 + c4] = v;
        }
        __syncthreads();
        for (int d = 0; d < 64; d += 4) {
            float4 a4[4], b4[4];
#pragma unroll
            for (int i = 0; i < 4; i++) a4[i] = *(const float4*)&smem[(ty * 4 + i) * 68 + d];
#pragma unroll
            for (int j = 0; j < 4; j++) b4[j] = *(const float4*)&smem[(tx * 4 + j) * 68 + d];
#pragma unroll
            for (int i = 0; i < 4; i++) {
#pragma unroll
                for (int j = 0; j < 4; j++) {
                    acc[i][j] += a4[i].x * b4[j].x + a4[i].y * b4[j].y +
                                 a4[i].z * b4[j].z + a4[i].w * b4[j].w;
                }
            }
        }
    }
#pragma unroll
    for (int i = 0; i < 4; i++)
#pragma unroll
        for (int j = 0; j < 4; j++) Gs[(ty * 4 + i) * 65 + tx * 4 + j] = acc[i][j];
    __syncthreads();
    if (tid < 64) {
        rn[tid] = rsqrtf(Gs[tid * 65 + tid]);
        wj[tid] = expf(all_pred[(b * 64 + tid) * 2 + 1]);
    }
    __syncthreads();
    // row softmax (thread r handles row r)
    if (tid < 64) {
        int r = tid;
        float mx = -1e30f;
        for (int c = 0; c < 64; c++) {
            float v = Gs[r * 65 + c] * wj[c];
            mx = fmaxf(mx, v);
        }
        float s = 0.f;
        for (int c = 0; c < 64; c++) {
            float e = expf(Gs[r * 65 + c] * wj[c] - mx);
            Gs[r * 65 + c] = e;
            s += e;
        }
        float inv = 1.f / s;
        float* Arow = Abuf + ((size_t)b * 64 + r) * 64;
        for (int c = 0; c < 64; c++) Arow[c] = Gs[r * 65 + c] * inv;
    }
    __syncthreads();
    // pivot * rn0 into smem
    float rn0 = rn[0];
    const float* piv = rowp[0];
    for (int c4 = tid; c4 < 512; c4 += 256) {
        float4 v = *(const float4*)(piv + c4 * 4);
        v.x *= rn0; v.y *= rn0; v.z *= rn0; v.w *= rn0;
        *(float4*)&smem[c4 * 4] = v;
    }
    __syncthreads();
    float* xo = xbuf + (size_t)b * 64 * Dd;
    for (int e4 = tid; e4 < 64 * 512; e4 += 256) {
        int row = e4 >> 9;
        int c4 = (e4 & 511) * 4;
        float4 v = *(const float4*)(rowp[row] + c4);
        float r_ = rn[row];
        float4 p = *(const float4*)&smem[c4];
        float4 o_;
        o_.x = v.x * r_ - p.x;
        o_.y = v.y * r_ - p.y;
        o_.z = v.z * r_ - p.z;
        o_.w = v.w * r_ - p.w;
        *(float4*)&xo[row * Dd + c4] = o_;
    }
}

// ---------------- generic fp32 GEMM: C = A[M,K] @ B[K,N'] (64x64 tiles) ----------------
// EPI 0: plain store; EPI 1: bias + PReLU
template <int EPI>
__global__ __launch_bounds__(256) void gemm_f32(
    const float* __restrict__ A, int lda,
    const float* __restrict__ Bm, int ldb,
    float* __restrict__ Cm, int ldc,
    int Kdim,
    const float* __restrict__ bias, const float* __restrict__ pre_a) {
    __shared__ float As[16 * 68];   // As[kk][m]
    __shared__ float Bs[16 * 68];   // Bs[kk][n]
    int tid = threadIdx.x;
    int ty = tid >> 4, tx = tid & 15;
    int m0 = blockIdx.y * 64, n0 = blockIdx.x * 64;
    int arow = tid >> 2, akp = tid & 3;
    int bkk = tid >> 4, bnp = tid & 15;
    float acc[4][4];
#pragma unroll
    for (int i = 0; i < 4; i++)
#pragma unroll
        for (int j = 0; j < 4; j++) acc[i][j] = 0.f;

    for (int k0 = 0; k0 < Kdim; k0 += 16) {
        __syncthreads();
        float4 av = *(const float4*)(A + (size_t)(m0 + arow) * lda + k0 + akp * 4);
        float4 bv = *(const float4*)(Bm + (size_t)(k0 + bkk) * ldb + n0 + bnp * 4);
        As[(akp * 4 + 0) * 68 + arow] = av.x;
        As[(akp * 4 + 1) * 68 + arow] = av.y;
        As[(akp * 4 + 2) * 68 + arow] = av.z;
        As[(akp * 4 + 3) * 68 + arow] = av.w;
        *(float4*)&Bs[bkk * 68 + bnp * 4] = bv;
        __syncthreads();
#pragma unroll
        for (int kk = 0; kk < 16; kk++) {
            float4 a4 = *(const float4*)&As[kk * 68 + ty * 4];
            float4 b4 = *(const float4*)&Bs[kk * 68 + tx * 4];
            float aa[4] = {a4.x, a4.y, a4.z, a4.w};
            float bb[4] = {b4.x, b4.y, b4.z, b4.w};
#pragma unroll
            for (int i = 0; i < 4; i++)
#pragma unroll
                for (int j = 0; j < 4; j++) acc[i][j] += aa[i] * bb[j];
        }
    }
#pragma unroll
    for (int i = 0; i < 4; i++) {
        int m = m0 + ty * 4 + i;
        int n = n0 + tx * 4;
        float4 o_;
        float v0 = acc[i][0], v1 = acc[i][1], v2 = acc[i][2], v3 = acc[i][3];
        if (EPI == 1) {
            v0 += bias[n + 0]; v1 += bias[n + 1]; v2 += bias[n + 2]; v3 += bias[n + 3];
            v0 = v0 >= 0.f ? v0 : pre_a[n + 0] * v0;
            v1 = v1 >= 0.f ? v1 : pre_a[n + 1] * v1;
            v2 = v2 >= 0.f ? v2 : pre_a[n + 2] * v2;
            v3 = v3 >= 0.f ? v3 : pre_a[n + 3] * v3;
        }
        o_.x = v0; o_.y = v1; o_.z = v2; o_.w = v3;
        *(float4*)(Cm + (size_t)m * ldc + n) = o_;
    }
}

// ---------------- per-batch mixing: out = relu(Ua + A@Ub + bias) ----------------
__global__ __launch_bounds__(256) void k_layer_agg(
    const float* __restrict__ Uab, const float* __restrict__ Abuf,
    const float* __restrict__ bias, float* __restrict__ outp, int Nc) {
    int b = blockIdx.x;
    int tid = threadIdx.x;
    __shared__ float Ast[64 * 68];   // A^T[k][m] layout: Ast[kk][m]
    __shared__ float Us[64 * 68];    // Us[kk][n]
    int ty = tid >> 4, tx = tid & 15;
    const float* Ab = Abuf + (size_t)b * 64 * 64;
    for (int e4 = tid; e4 < 1024; e4 += 256) {
        float4 v = *(const float4*)(Ab + e4 * 4);
        int row = e4 >> 4;           // m index
        int c4 = (e4 & 15) * 4;      // k index base
        Ast[(c4 + 0) * 68 + row] = v.x;
        Ast[(c4 + 1) * 68 + row] = v.y;
        Ast[(c4 + 2) * 68 + row] = v.z;
        Ast[(c4 + 3) * 68 + row] = v.w;
    }
    int ldU = 2 * Nc;
    const float* Ua = Uab;
    const float* Ub = Uab + Nc;
    for (int n0 = 0; n0 < Nc; n0 += 64) {
        __syncthreads();
#pragma unroll
        for (int kq = 0; kq < 4; kq++) {
            int e4 = tid + kq * 256;
            int row = e4 >> 4;
            int c4 = (e4 & 15) * 4;
            float4 v = *(const float4*)(Ub + (size_t)(b * 64 + row) * ldU + n0 + c4);
            *(float4*)&Us[row * 68 + c4] = v;
        }
        __syncthreads();
        float acc[4][4];
#pragma unroll
        for (int i = 0; i < 4; i++)
#pragma unroll
            for (int j = 0; j < 4; j++) acc[i][j] = 0.f;
        for (int kk = 0; kk < 64; kk++) {
            float4 a4 = *(const float4*)&Ast[kk * 68 + ty * 4];
            float4 b4 = *(const float4*)&Us[kk * 68 + tx * 4];
            float aa[4] = {a4.x, a4.y, a4.z, a4.w};
            float bb[4] = {b4.x, b4.y, b4.z, b4.w};
#pragma unroll
            for (int i = 0; i < 4; i++)
#pragma unroll
                for (int j = 0; j < 4; j++) acc[i][j] += aa[i] * bb[j];
        }
#pragma unroll
        for (int i = 0; i < 4; i++) {
            int m = b * 64 + ty * 4 + i;
            int n = n0 + tx * 4;
            float4 ua = *(const float4*)(Ua + (size_t)m * ldU + n);
            float4 o_;
            o_.x = fmaxf(ua.x + acc[i][0] + bias[n + 0], 0.f);
            o_.y = fmaxf(ua.y + acc[i][1] + bias[n + 1], 0.f);
            o_.z = fmaxf(ua.z + acc[i][2] + bias[n + 2], 0.f);
            o_.w = fmaxf(ua.w + acc[i][3] + bias[n + 3], 0.f);
            *(float4*)(outp + (size_t)m * Nc + n) = o_;
        }
        __syncthreads();
    }
}

// ---------------- logits + 2-class softmax ----------------
__global__ __launch_bounds__(256) void k_logits(
    const float* __restrict__ h, const float* __restrict__ Wc2,
    const float* __restrict__ bc2, float* __restrict__ pred) {
    __shared__ float p0[256], p1[256];
    int tid = threadIdx.x;
    int r = tid >> 2, s = tid & 3;
    int m = blockIdx.x * 64 + r;
    const float* hr = h + (size_t)m * 256;
    float l0 = 0.f, l1 = 0.f;
    for (int k = s; k < 256; k += 4) {
        float hv = hr[k];
        l0 += hv * Wc2[2 * k];
        l1 += hv * Wc2[2 * k + 1];
    }
    p0[tid] = l0;
    p1[tid] = l1;
    __syncthreads();
    if (s == 0) {
        float L0 = p0[tid] + p0[tid + 1] + p0[tid + 2] + p0[tid + 3] + bc2[0];
        float L1 = p1[tid] + p1[tid + 1] + p1[tid + 2] + p1[tid + 3] + bc2[1];
        float mx = fmaxf(L0, L1);
        float e0 = expf(L0 - mx), e1 = expf(L1 - mx);
        float inv = 1.f / (e0 + e1);
        pred[2 * m] = e0 * inv;
        pred[2 * m + 1] = e1 * inv;
    }
}

// ---------------- launch ----------------
extern "C" void kernel_launch(void* const* d_in, const int* in_sizes, int n_in,
                              void* d_out, int out_size, void* d_ws, size_t ws_size,
                              hipStream_t stream) {
    const int* indexes = (const int*)d_in[0];
    const float* features = (const float*)d_in[1];
    const int* labels = (const int*)d_in[2];
    const int* knn = (const int*)d_in[5];
    const float* all_pred = (const float*)d_in[6];
    const float* W1 = (const float*)d_in[7];
    const float* b1 = (const float*)d_in[8];
    const float* W2 = (const float*)d_in[9];
    const float* b2 = (const float*)d_in[10];
    const float* Wc1 = (const float*)d_in[11];
    const float* bc1 = (const float*)d_in[12];
    const float* pre_a = (const float*)d_in[13];
    const float* Wc2 = (const float*)d_in[14];
    const float* bc2 = (const float*)d_in[15];
    float* out = (float*)d_out;

    char* w = (char*)d_ws;
    size_t o = 0;
    auto carve = [&](size_t bytes) -> char* {
        char* p = w + o;
        o += (bytes + 255) & ~(size_t)255;
        return p;
    };
    int* cnt = (int*)carve((size_t)Cc * 4);
    int* off = (int*)carve((size_t)Cc * 4);
    int* pos = (int*)carve((size_t)Cc * 4);
    int* rowidx = (int*)carve((size_t)Nn * 4);
    float* clu_mean = (float*)carve((size_t)Cc * Dd * 4);       // 41 MB
    float* xbuf = (float*)carve((size_t)Bq * Kn * Dd * 4);      // 134 MB
    float* Abuf = (float*)carve((size_t)Bq * Kn * Kn * 4);      // 4.2 MB
    float* U = (float*)carve((size_t)Bq * Kn * 2 * NHID * 4);   // 67 MB
    // aliases (lifetimes are disjoint):
    float* x1 = clu_mean;                       // [16384,512] 33.5 MB <= 41 MB
    float* V = U;                               // [16384,512]
    float* x2 = xbuf;                           // [16384,256]
    float* h = xbuf + (size_t)Bq * Kn * H2d;    // [16384,256]

    float* simm_out = out + (size_t)Bq * Kn * 2;

    // 1) cluster bucketing
    k_zero_int<<<(Cc + 255) / 256, 256, 0, stream>>>(cnt, Cc);
    k_count<<<(Nn + 255) / 256, 256, 0, stream>>>(labels, cnt, Nn);
    k_scan<<<1, 1024, 0, stream>>>(cnt, off, pos, Cc);
    k_scatter<<<(Nn + 255) / 256, 256, 0, stream>>>(labels, pos, rowidx, Nn);

    // 2) cluster means + simm output
    k_meansimm<<<Cc, 256, 0, stream>>>(features, rowidx, off, cnt, clu_mean, simm_out);

    // 3) per-batch adjacency + normalized/centered x
    k_build_ax<<<Bq, 256, 0, stream>>>(features, clu_mean, labels, indexes, knn,
                                       all_pred, Abuf, xbuf);

    // 4) U = [x @ W1a | x @ W1b]   (W1 is [4096, 512]; rows 0..2047 = a, 2048.. = b)
    {
        dim3 g(NHID / 64, (Bq * Kn) / 64);
        gemm_f32<0><<<g, 256, 0, stream>>>(xbuf, Dd, W1, NHID, U, 2 * NHID,
                                           Dd, nullptr, nullptr);
        gemm_f32<0><<<g, 256, 0, stream>>>(xbuf, Dd, W1 + (size_t)Dd * NHID, NHID,
                                           U + NHID, 2 * NHID, Dd, nullptr, nullptr);
    }
    // 5) x1 = relu(Ua + A@Ub + b1)
    k_layer_agg<<<Bq, 256, 0, stream>>>(U, Abuf, b1, x1, NHID);

    // 6) V = [x1 @ W2a | x1 @ W2b]  (W2 is [1024, 256])
    {
        dim3 g(H2d / 64, (Bq * Kn) / 64);
        gemm_f32<0><<<g, 256, 0, stream>>>(x1, NHID, W2, H2d, V, 2 * H2d,
                                           NHID, nullptr, nullptr);
        gemm_f32<0><<<g, 256, 0, stream>>>(x1, NHID, W2 + (size_t)NHID * H2d, H2d,
                                           V + H2d, 2 * H2d, NHID, nullptr, nullptr);
    }
    // 7) x2 = relu(Va + A@Vb + b2)
    k_layer_agg<<<Bq, 256, 0, stream>>>(V, Abuf, b2, x2, H2d);

    // 8) h = prelu(x2 @ Wc1 + bc1)
    {
        dim3 g(H2d / 64, (Bq * Kn) / 64);
        gemm_f32<1><<<g, 256, 0, stream>>>(x2, H2d, Wc1, H2d, h, H2d,
                                           H2d, bc1, pre_a);
    }
    // 9) logits + softmax -> pred
    k_logits<<<(Bq * Kn) / 64, 256, 0, stream>>>(h, Wc2, bc2, out);

    (void)in_sizes; (void)n_in; (void)out_size; (void)ws_size;
}

// Round 2
// 1106.833 us; speedup vs baseline: 1.7710x; 1.7710x over previous
//
#include <hip/hip_runtime.h>
#include <math.h>

#define Bq 256
#define Kn 64
#define Dd 2048
#define Nn 50000
#define Cc 5000
#define NHID 512
#define H2d 256

typedef __attribute__((ext_vector_type(8))) __bf16 bf16x8;
typedef __attribute__((ext_vector_type(4))) float f32x4;

__device__ __forceinline__ unsigned short f2bf(float f) {
    union { float f; unsigned int u; } v;
    v.f = f;
    unsigned int u = v.u;
    unsigned int r = (u + 0x7fff + ((u >> 16) & 1)) >> 16;   // RNE
    return (unsigned short)r;
}

// ---------------- small utility kernels ----------------

__global__ void k_zero_int(int* __restrict__ p, int n) {
    int i = blockIdx.x * 256 + threadIdx.x;
    if (i < n) p[i] = 0;
}

__global__ void k_count(const int* __restrict__ labels, int* __restrict__ cnt, int n) {
    int i = blockIdx.x * 256 + threadIdx.x;
    if (i < n) atomicAdd(&cnt[labels[i]], 1);
}

__global__ __launch_bounds__(1024) void k_scan(const int* __restrict__ cnt,
                                               int* __restrict__ off,
                                               int* __restrict__ pos, int C) {
    __shared__ int s[1024];
    __shared__ int carry;
    int tid = threadIdx.x;
    if (tid == 0) carry = 0;
    __syncthreads();
    for (int base = 0; base < C; base += 1024) {
        int i = base + tid;
        int v = (i < C) ? cnt[i] : 0;
        s[tid] = v;
        __syncthreads();
        for (int o = 1; o < 1024; o <<= 1) {
            int t = (tid >= o) ? s[tid - o] : 0;
            __syncthreads();
            s[tid] += t;
            __syncthreads();
        }
        int excl = carry + s[tid] - v;
        if (i < C) { off[i] = excl; pos[i] = excl; }
        __syncthreads();
        if (tid == 0) carry += s[1023];
        __syncthreads();
    }
}

__global__ void k_scatter(const int* __restrict__ labels, int* __restrict__ pos,
                          int* __restrict__ rowidx, int n) {
    int i = blockIdx.x * 256 + threadIdx.x;
    if (i < n) {
        int p = atomicAdd(&pos[labels[i]], 1);
        rowidx[p] = i;
    }
}

// ---------------- cluster mean + simm ----------------
__global__ __launch_bounds__(256) void k_meansimm(
    const float* __restrict__ feat, const int* __restrict__ rowidx,
    const int* __restrict__ off, const int* __restrict__ cnt,
    float* __restrict__ clu_mean, float* __restrict__ simm) {
    int c = blockIdx.x;
    int t = threadIdx.x;
    int n = cnt[c], st = off[c];
    float acc[8];
#pragma unroll
    for (int j = 0; j < 8; j++) acc[j] = 0.f;
    for (int r = 0; r < n; r++) {
        const float* row = feat + (size_t)rowidx[st + r] * Dd;
#pragma unroll
        for (int j = 0; j < 8; j++) acc[j] += row[j * 256 + t];
    }
    float sc = 1.f / (float)(n > 1 ? n : 1);
    float ss = 0.f;
    float* outr = clu_mean + (size_t)c * Dd;
#pragma unroll
    for (int j = 0; j < 8; j++) {
        float m = acc[j] * sc;
        outr[j * 256 + t] = m;
        ss += m * m;
    }
    __shared__ float red[256];
    red[t] = ss;
    __syncthreads();
    for (int s2 = 128; s2 > 0; s2 >>= 1) {
        if (t < s2) red[t] += red[t + s2];
        __syncthreads();
    }
    if (t == 0) simm[c] = red[0];
}

// ---------------- per-batch: A + x (x written as bf16) ----------------
__global__ __launch_bounds__(256) void k_build_ax(
    const float* __restrict__ feat, const float* __restrict__ clu_mean,
    const int* __restrict__ labels, const int* __restrict__ indexes,
    const int* __restrict__ knn, const float* __restrict__ all_pred,
    float* __restrict__ Abuf, unsigned short* __restrict__ xbuf) {
    int b = blockIdx.x;
    int tid = threadIdx.x;
    __shared__ float smem[64 * 68];
    __shared__ float Gs[64 * 65];
    __shared__ const float* rowp[64];
    __shared__ float wj[64], rn[64];

    if (tid < 64) {
        int j = tid;
        const float* p;
        if (j == 0) p = feat + (size_t)indexes[b] * Dd;
        else        p = clu_mean + (size_t)labels[knn[b * 64 + j]] * Dd;
        rowp[j] = p;
    }

    int ty = tid >> 4, tx = tid & 15;
    float acc[4][4];
#pragma unroll
    for (int i = 0; i < 4; i++)
#pragma unroll
        for (int j = 0; j < 4; j++) acc[i][j] = 0.f;

    for (int ch = 0; ch < 32; ch++) {
        int d0 = ch * 64;
        __syncthreads();
#pragma unroll
        for (int kq = 0; kq < 4; kq++) {
            int e4 = tid + kq * 256;
            int row = e4 >> 4;
            int c4 = (e4 & 15) * 4;
            float4 v = *(const float4*)(rowp[row] + d0 + c4);
            *(float4*)&smem[row * 68 + c4] = v;
        }
        __syncthreads();
        for (int d = 0; d < 64; d += 4) {
            float4 a4[4], b4[4];
#pragma unroll
            for (int i = 0; i < 4; i++) a4[i] = *(const float4*)&smem[(ty * 4 + i) * 68 + d];
#pragma unroll
            for (int j = 0; j < 4; j++) b4[j] = *(const float4*)&smem[(tx * 4 + j) * 68 + d];
#pragma unroll
            for (int i = 0; i < 4; i++) {
#pragma unroll
                for (int j = 0; j < 4; j++) {
                    acc[i][j] += a4[i].x * b4[j].x + a4[i].y * b4[j].y +
                                 a4[i].z * b4[j].z + a4[i].w * b4[j].w;
                }
            }
        }
    }
#pragma unroll
    for (int i = 0; i < 4; i++)
#pragma unroll
        for (int j = 0; j < 4; j++) Gs[(ty * 4 + i) * 65 + tx * 4 + j] = acc[i][j];
    __syncthreads();
    if (tid < 64) {
        rn[tid] = rsqrtf(Gs[tid * 65 + tid]);
        wj[tid] = expf(all_pred[(b * 64 + tid) * 2 + 1]);
    }
    __syncthreads();
    if (tid < 64) {
        int r = tid;
        float mx = -1e30f;
        for (int c = 0; c < 64; c++) {
            float v = Gs[r * 65 + c] * wj[c];
            mx = fmaxf(mx, v);
        }
        float s = 0.f;
        for (int c = 0; c < 64; c++) {
            float e = expf(Gs[r * 65 + c] * wj[c] - mx);
            Gs[r * 65 + c] = e;
            s += e;
        }
        float inv = 1.f / s;
        float* Arow = Abuf + ((size_t)b * 64 + r) * 64;
        for (int c = 0; c < 64; c++) Arow[c] = Gs[r * 65 + c] * inv;
    }
    __syncthreads();
    float rn0 = rn[0];
    const float* piv = rowp[0];
    for (int c4 = tid; c4 < 512; c4 += 256) {
        float4 v = *(const float4*)(piv + c4 * 4);
        v.x *= rn0; v.y *= rn0; v.z *= rn0; v.w *= rn0;
        *(float4*)&smem[c4 * 4] = v;
    }
    __syncthreads();
    unsigned short* xo = xbuf + (size_t)b * 64 * Dd;
    for (int e4 = tid; e4 < 64 * 512; e4 += 256) {
        int row = e4 >> 9;
        int c4 = (e4 & 511) * 4;
        float4 v = *(const float4*)(rowp[row] + c4);
        float r_ = rn[row];
        float4 p = *(const float4*)&smem[c4];
        ushort4 o_;
        o_.x = f2bf(v.x * r_ - p.x);
        o_.y = f2bf(v.y * r_ - p.y);
        o_.z = f2bf(v.z * r_ - p.z);
        o_.w = f2bf(v.w * r_ - p.w);
        *(ushort4*)&xo[row * Dd + c4] = o_;
    }
}

// ---------------- W1 repack: [4096,512] f32 -> Bp[k/8][1024][8] bf16 ----------------
__global__ __launch_bounds__(256) void k_pack_w1(const float* __restrict__ W1,
                                                 unsigned short* __restrict__ Bp) {
    int idx = blockIdx.x * 256 + threadIdx.x;   // [0, 256*1024)
    int kb = idx >> 10;
    int n = idx & 1023;
    ushort4 lo, hi;
    float v[8];
#pragma unroll
    for (int j = 0; j < 8; j++) {
        int k = kb * 8 + j;
        v[j] = (n < 512) ? W1[(size_t)k * 512 + n]
                         : W1[(size_t)(2048 + k) * 512 + (n - 512)];
    }
    lo.x = f2bf(v[0]); lo.y = f2bf(v[1]); lo.z = f2bf(v[2]); lo.w = f2bf(v[3]);
    hi.x = f2bf(v[4]); hi.y = f2bf(v[5]); hi.z = f2bf(v[6]); hi.w = f2bf(v[7]);
    *(ushort4*)&Bp[(size_t)idx * 8] = lo;
    *(ushort4*)&Bp[(size_t)idx * 8 + 4] = hi;
}

// ---------------- bf16 MFMA GEMM: C[M,N] = A[M,K] @ Bp (m97 structure) ----------------
// A bf16 row-major (lda=K); Bp packed [K/8][N][8] bf16; C fp32 row-major (ldc=N)
__global__ __launch_bounds__(256) void gemm_bf16_mfma(
    const unsigned short* __restrict__ A, const unsigned short* __restrict__ Bp,
    float* __restrict__ C, int M, int K, int N) {
    __shared__ unsigned short Asm[128 * 32];    // [row][32] bf16, 64B rows, 8 KB
    __shared__ unsigned short Bsm[4 * 128 * 8]; // [quad][n][8], 8 KB
    int tid = threadIdx.x;
    int wave = tid >> 6, lane = tid & 63;
    int quad = lane >> 4, l16 = lane & 15;
    int m0 = blockIdx.y * 128, n0 = blockIdx.x * 128;
    int wm = (wave >> 1) * 64, wn = (wave & 1) * 64;

    f32x4 acc[4][4];
#pragma unroll
    for (int i = 0; i < 4; i++)
#pragma unroll
        for (int j = 0; j < 4; j++) acc[i][j] = (f32x4){0.f, 0.f, 0.f, 0.f};

    // staging base pointers (per-lane global, wave-uniform LDS)
    int ia0 = wave * 2, ia1 = wave * 2 + 1;
    const unsigned short* gA0 = A + (size_t)(m0 + ia0 * 16 + (lane >> 2)) * K + (lane & 3) * 8;
    const unsigned short* gA1 = gA0 + (size_t)16 * K;
    const unsigned short* gB0 = Bp + (size_t)(n0 + lane) * 8 + (size_t)wave * N * 8;

    for (int k0 = 0; k0 < K; k0 += 32) {
        __syncthreads();
        size_t bko = (size_t)(k0 >> 3) * N * 8;
        __builtin_amdgcn_global_load_lds(
            (const __attribute__((address_space(1))) void*)(gA0 + k0),
            (__attribute__((address_space(3))) void*)(Asm + ia0 * 512), 16, 0, 0);
        __builtin_amdgcn_global_load_lds(
            (const __attribute__((address_space(1))) void*)(gA1 + k0),
            (__attribute__((address_space(3))) void*)(Asm + ia1 * 512), 16, 0, 0);
        __builtin_amdgcn_global_load_lds(
            (const __attribute__((address_space(1))) void*)(gB0 + bko),
            (__attribute__((address_space(3))) void*)(Bsm + wave * 1024), 16, 0, 0);
        __builtin_amdgcn_global_load_lds(
            (const __attribute__((address_space(1))) void*)(gB0 + bko + 512),
            (__attribute__((address_space(3))) void*)(Bsm + wave * 1024 + 512), 16, 0, 0);
        __syncthreads();

        bf16x8 a[4], b[4];
#pragma unroll
        for (int i = 0; i < 4; i++)
            a[i] = *(const bf16x8*)&Asm[(wm + i * 16 + l16) * 32 + quad * 8];
#pragma unroll
        for (int j = 0; j < 4; j++)
            b[j] = *(const bf16x8*)&Bsm[quad * 1024 + (wn + j * 16 + l16) * 8];
#pragma unroll
        for (int i = 0; i < 4; i++)
#pragma unroll
            for (int j = 0; j < 4; j++)
                acc[i][j] = __builtin_amdgcn_mfma_f32_16x16x32_bf16(
                    a[i], b[j], acc[i][j], 0, 0, 0);
    }

#pragma unroll
    for (int i = 0; i < 4; i++) {
#pragma unroll
        for (int j = 0; j < 4; j++) {
#pragma unroll
            for (int r = 0; r < 4; r++) {
                int row = m0 + wm + i * 16 + quad * 4 + r;
                int col = n0 + wn + j * 16 + l16;
                C[(size_t)row * N + col] = acc[i][j][r];
            }
        }
    }
}

// ---------------- generic fp32 GEMM (64x64 tiles) ----------------
template <int EPI>
__global__ __launch_bounds__(256) void gemm_f32(
    const float* __restrict__ A, int lda,
    const float* __restrict__ Bm, int ldb,
    float* __restrict__ Cm, int ldc,
    int Kdim,
    const float* __restrict__ bias, const float* __restrict__ pre_a) {
    __shared__ float As[16 * 68];
    __shared__ float Bs[16 * 68];
    int tid = threadIdx.x;
    int ty = tid >> 4, tx = tid & 15;
    int m0 = blockIdx.y * 64, n0 = blockIdx.x * 64;
    int arow = tid >> 2, akp = tid & 3;
    int bkk = tid >> 4, bnp = tid & 15;
    float acc[4][4];
#pragma unroll
    for (int i = 0; i < 4; i++)
#pragma unroll
        for (int j = 0; j < 4; j++) acc[i][j] = 0.f;

    for (int k0 = 0; k0 < Kdim; k0 += 16) {
        __syncthreads();
        float4 av = *(const float4*)(A + (size_t)(m0 + arow) * lda + k0 + akp * 4);
        float4 bv = *(const float4*)(Bm + (size_t)(k0 + bkk) * ldb + n0 + bnp * 4);
        As[(akp * 4 + 0) * 68 + arow] = av.x;
        As[(akp * 4 + 1) * 68 + arow] = av.y;
        As[(akp * 4 + 2) * 68 + arow] = av.z;
        As[(akp * 4 + 3) * 68 + arow] = av.w;
        *(float4*)&Bs[bkk * 68 + bnp * 4] = bv;
        __syncthreads();
#pragma unroll
        for (int kk = 0; kk < 16; kk++) {
            float4 a4 = *(const float4*)&As[kk * 68 + ty * 4];
            float4 b4 = *(const float4*)&Bs[kk * 68 + tx * 4];
            float aa[4] = {a4.x, a4.y, a4.z, a4.w};
            float bb[4] = {b4.x, b4.y, b4.z, b4.w};
#pragma unroll
            for (int i = 0; i < 4; i++)
#pragma unroll
                for (int j = 0; j < 4; j++) acc[i][j] += aa[i] * bb[j];
        }
    }
#pragma unroll
    for (int i = 0; i < 4; i++) {
        int m = m0 + ty * 4 + i;
        int n = n0 + tx * 4;
        float4 o_;
        float v0 = acc[i][0], v1 = acc[i][1], v2 = acc[i][2], v3 = acc[i][3];
        if (EPI == 1) {
            v0 += bias[n + 0]; v1 += bias[n + 1]; v2 += bias[n + 2]; v3 += bias[n + 3];
            v0 = v0 >= 0.f ? v0 : pre_a[n + 0] * v0;
            v1 = v1 >= 0.f ? v1 : pre_a[n + 1] * v1;
            v2 = v2 >= 0.f ? v2 : pre_a[n + 2] * v2;
            v3 = v3 >= 0.f ? v3 : pre_a[n + 3] * v3;
        }
        o_.x = v0; o_.y = v1; o_.z = v2; o_.w = v3;
        *(float4*)(Cm + (size_t)m * ldc + n) = o_;
    }
}

// ---------------- per-batch mixing: out = relu(Ua + A@Ub + bias) ----------------
__global__ __launch_bounds__(256) void k_layer_agg(
    const float* __restrict__ Uab, const float* __restrict__ Abuf,
    const float* __restrict__ bias, float* __restrict__ outp, int Nc) {
    int b = blockIdx.x;
    int tid = threadIdx.x;
    __shared__ float Ast[64 * 68];
    __shared__ float Us[64 * 68];
    int ty = tid >> 4, tx = tid & 15;
    const float* Ab = Abuf + (size_t)b * 64 * 64;
    for (int e4 = tid; e4 < 1024; e4 += 256) {
        float4 v = *(const float4*)(Ab + e4 * 4);
        int row = e4 >> 4;
        int c4 = (e4 & 15) * 4;
        Ast[(c4 + 0) * 68 + row] = v.x;
        Ast[(c4 + 1) * 68 + row] = v.y;
        Ast[(c4 + 2) * 68 + row] = v.z;
        Ast[(c4 + 3) * 68 + row] = v.w;
    }
    int ldU = 2 * Nc;
    const float* Ua = Uab;
    const float* Ub = Uab + Nc;
    for (int n0 = 0; n0 < Nc; n0 += 64) {
        __syncthreads();
#pragma unroll
        for (int kq = 0; kq < 4; kq++) {
            int e4 = tid + kq * 256;
            int row = e4 >> 4;
            int c4 = (e4 & 15) * 4;
            float4 v = *(const float4*)(Ub + (size_t)(b * 64 + row) * ldU + n0 + c4);
            *(float4*)&Us[row * 68 + c4] = v;
        }
        __syncthreads();
        float acc[4][4];
#pragma unroll
        for (int i = 0; i < 4; i++)
#pragma unroll
            for (int j = 0; j < 4; j++) acc[i][j] = 0.f;
        for (int kk = 0; kk < 64; kk++) {
            float4 a4 = *(const float4*)&Ast[kk * 68 + ty * 4];
            float4 b4 = *(const float4*)&Us[kk * 68 + tx * 4];
            float aa[4] = {a4.x, a4.y, a4.z, a4.w};
            float bb[4] = {b4.x, b4.y, b4.z, b4.w};
#pragma unroll
            for (int i = 0; i < 4; i++)
#pragma unroll
                for (int j = 0; j < 4; j++) acc[i][j] += aa[i] * bb[j];
        }
#pragma unroll
        for (int i = 0; i < 4; i++) {
            int m = b * 64 + ty * 4 + i;
            int n = n0 + tx * 4;
            float4 ua = *(const float4*)(Ua + (size_t)m * ldU + n);
            float4 o_;
            o_.x = fmaxf(ua.x + acc[i][0] + bias[n + 0], 0.f);
            o_.y = fmaxf(ua.y + acc[i][1] + bias[n + 1], 0.f);
            o_.z = fmaxf(ua.z + acc[i][2] + bias[n + 2], 0.f);
            o_.w = fmaxf(ua.w + acc[i][3] + bias[n + 3], 0.f);
            *(float4*)(outp + (size_t)m * Nc + n) = o_;
        }
        __syncthreads();
    }
}

// ---------------- logits + 2-class softmax ----------------
__global__ __launch_bounds__(256) void k_logits(
    const float* __restrict__ h, const float* __restrict__ Wc2,
    const float* __restrict__ bc2, float* __restrict__ pred) {
    __shared__ float p0[256], p1[256];
    int tid = threadIdx.x;
    int r = tid >> 2, s = tid & 3;
    int m = blockIdx.x * 64 + r;
    const float* hr = h + (size_t)m * 256;
    float l0 = 0.f, l1 = 0.f;
    for (int k = s; k < 256; k += 4) {
        float hv = hr[k];
        l0 += hv * Wc2[2 * k];
        l1 += hv * Wc2[2 * k + 1];
    }
    p0[tid] = l0;
    p1[tid] = l1;
    __syncthreads();
    if (s == 0) {
        float L0 = p0[tid] + p0[tid + 1] + p0[tid + 2] + p0[tid + 3] + bc2[0];
        float L1 = p1[tid] + p1[tid + 1] + p1[tid + 2] + p1[tid + 3] + bc2[1];
        float mx = fmaxf(L0, L1);
        float e0 = expf(L0 - mx), e1 = expf(L1 - mx);
        float inv = 1.f / (e0 + e1);
        pred[2 * m] = e0 * inv;
        pred[2 * m + 1] = e1 * inv;
    }
}

// ---------------- launch ----------------
extern "C" void kernel_launch(void* const* d_in, const int* in_sizes, int n_in,
                              void* d_out, int out_size, void* d_ws, size_t ws_size,
                              hipStream_t stream) {
    const int* indexes = (const int*)d_in[0];
    const float* features = (const float*)d_in[1];
    const int* labels = (const int*)d_in[2];
    const int* knn = (const int*)d_in[5];
    const float* all_pred = (const float*)d_in[6];
    const float* W1 = (const float*)d_in[7];
    const float* b1 = (const float*)d_in[8];
    const float* W2 = (const float*)d_in[9];
    const float* b2 = (const float*)d_in[10];
    const float* Wc1 = (const float*)d_in[11];
    const float* bc1 = (const float*)d_in[12];
    const float* pre_a = (const float*)d_in[13];
    const float* Wc2 = (const float*)d_in[14];
    const float* bc2 = (const float*)d_in[15];
    float* out = (float*)d_out;

    char* w = (char*)d_ws;
    size_t o = 0;
    auto carve = [&](size_t bytes) -> char* {
        char* p = w + o;
        o += (bytes + 255) & ~(size_t)255;
        return p;
    };
    int* cnt = (int*)carve((size_t)Cc * 4);
    int* off = (int*)carve((size_t)Cc * 4);
    int* pos = (int*)carve((size_t)Cc * 4);
    int* rowidx = (int*)carve((size_t)Nn * 4);
    float* clu_mean = (float*)carve((size_t)Cc * Dd * 4);             // 41 MB
    unsigned short* xbuf = (unsigned short*)carve((size_t)Bq * Kn * Dd * 2);  // 67 MB (bf16)
    float* Abuf = (float*)carve((size_t)Bq * Kn * Kn * 4);            // 4.2 MB
    float* U = (float*)carve((size_t)Bq * Kn * 2 * NHID * 4);         // 67 MB
    unsigned short* Bp = (unsigned short*)carve((size_t)(Dd / 8) * 1024 * 8 * 2); // 4 MB
    // aliases (lifetimes disjoint):
    float* x1 = clu_mean;                          // [16384,512] fp32, 33.5 MB <= 41 MB
    float* V = U;                                  // [16384,512]
    float* x2 = (float*)xbuf;                      // [16384,256] fp32 16.7 MB
    float* h = (float*)xbuf + (size_t)Bq * Kn * H2d;  // next 16.7 MB (region is 67 MB)

    float* simm_out = out + (size_t)Bq * Kn * 2;

    // 1) cluster bucketing
    k_zero_int<<<(Cc + 255) / 256, 256, 0, stream>>>(cnt, Cc);
    k_count<<<(Nn + 255) / 256, 256, 0, stream>>>(labels, cnt, Nn);
    k_scan<<<1, 1024, 0, stream>>>(cnt, off, pos, Cc);
    k_scatter<<<(Nn + 255) / 256, 256, 0, stream>>>(labels, pos, rowidx, Nn);

    // 2) cluster means + simm output
    k_meansimm<<<Cc, 256, 0, stream>>>(features, rowidx, off, cnt, clu_mean, simm_out);

    // 3) per-batch adjacency + normalized/centered x (bf16)
    k_build_ax<<<Bq, 256, 0, stream>>>(features, clu_mean, labels, indexes, knn,
                                       all_pred, Abuf, xbuf);

    // 3b) pack W1 -> Bp (bf16, MFMA-native)
    k_pack_w1<<<1024, 256, 0, stream>>>(W1, Bp);

    // 4) U = [x @ W1a | x @ W1b] via one bf16 MFMA GEMM (M=16384, N=1024, K=2048)
    {
        dim3 g(1024 / 128, (Bq * Kn) / 128);
        gemm_bf16_mfma<<<g, 256, 0, stream>>>(xbuf, Bp, U, Bq * Kn, Dd, 1024);
    }
    // 5) x1 = relu(Ua + A@Ub + b1)
    k_layer_agg<<<Bq, 256, 0, stream>>>(U, Abuf, b1, x1, NHID);

    // 6) V = [x1 @ W2a | x1 @ W2b]  (fp32)
    {
        dim3 g(H2d / 64, (Bq * Kn) / 64);
        gemm_f32<0><<<g, 256, 0, stream>>>(x1, NHID, W2, H2d, V, 2 * H2d,
                                           NHID, nullptr, nullptr);
        gemm_f32<0><<<g, 256, 0, stream>>>(x1, NHID, W2 + (size_t)NHID * H2d, H2d,
                                           V + H2d, 2 * H2d, NHID, nullptr, nullptr);
    }
    // 7) x2 = relu(Va + A@Vb + b2)
    k_layer_agg<<<Bq, 256, 0, stream>>>(V, Abuf, b2, x2, H2d);

    // 8) h = prelu(x2 @ Wc1 + bc1)
    {
        dim3 g(H2d / 64, (Bq * Kn) / 64);
        gemm_f32<1><<<g, 256, 0, stream>>>(x2, H2d, Wc1, H2d, h, H2d,
                                           H2d, bc1, pre_a);
    }
    // 9) logits + softmax -> pred
    k_logits<<<(Bq * Kn) / 64, 256, 0, stream>>>(h, Wc2, bc2, out);

    (void)in_sizes; (void)n_in; (void)out_size; (void)ws_size;
}

// Round 3
// 990.959 us; speedup vs baseline: 1.9781x; 1.1169x over previous
//
#include <hip/hip_runtime.h>
#include <math.h>

#define Bq 256
#define Kn 64
#define Dd 2048
#define Nn 50000
#define Cc 5000
#define NHID 512
#define H2d 256

typedef __attribute__((ext_vector_type(8))) __bf16 bf16x8;
typedef __attribute__((ext_vector_type(4))) float f32x4;

__device__ __forceinline__ unsigned short f2bf(float f) {
    union { float f; unsigned int u; } v;
    v.f = f;
    unsigned int u = v.u;
    unsigned int r = (u + 0x7fff + ((u >> 16) & 1)) >> 16;   // RNE
    return (unsigned short)r;
}

// ---------------- small utility kernels ----------------

__global__ void k_zero_int(int* __restrict__ p, int n) {
    int i = blockIdx.x * 256 + threadIdx.x;
    if (i < n) p[i] = 0;
}

__global__ void k_count(const int* __restrict__ labels, int* __restrict__ cnt, int n) {
    int i = blockIdx.x * 256 + threadIdx.x;
    if (i < n) atomicAdd(&cnt[labels[i]], 1);
}

__global__ __launch_bounds__(1024) void k_scan(const int* __restrict__ cnt,
                                               int* __restrict__ off,
                                               int* __restrict__ pos, int C) {
    __shared__ int s[1024];
    __shared__ int carry;
    int tid = threadIdx.x;
    if (tid == 0) carry = 0;
    __syncthreads();
    for (int base = 0; base < C; base += 1024) {
        int i = base + tid;
        int v = (i < C) ? cnt[i] : 0;
        s[tid] = v;
        __syncthreads();
        for (int o = 1; o < 1024; o <<= 1) {
            int t = (tid >= o) ? s[tid - o] : 0;
            __syncthreads();
            s[tid] += t;
            __syncthreads();
        }
        int excl = carry + s[tid] - v;
        if (i < C) { off[i] = excl; pos[i] = excl; }
        __syncthreads();
        if (tid == 0) carry += s[1023];
        __syncthreads();
    }
}

__global__ void k_scatter(const int* __restrict__ labels, int* __restrict__ pos,
                          int* __restrict__ rowidx, int n) {
    int i = blockIdx.x * 256 + threadIdx.x;
    if (i < n) {
        int p = atomicAdd(&pos[labels[i]], 1);
        rowidx[p] = i;
    }
}

// ---------------- cluster mean + simm (float4 loads) ----------------
__global__ __launch_bounds__(256) void k_meansimm(
    const float* __restrict__ feat, const int* __restrict__ rowidx,
    const int* __restrict__ off, const int* __restrict__ cnt,
    float* __restrict__ clu_mean, float* __restrict__ simm) {
    int c = blockIdx.x;
    int t = threadIdx.x;
    int n = cnt[c], st = off[c];
    float4 a0 = {0.f, 0.f, 0.f, 0.f}, a1 = {0.f, 0.f, 0.f, 0.f};
    for (int r = 0; r < n; r++) {
        const float* row = feat + (size_t)rowidx[st + r] * Dd;
        float4 v0 = *(const float4*)(row + t * 4);
        float4 v1 = *(const float4*)(row + 1024 + t * 4);
        a0.x += v0.x; a0.y += v0.y; a0.z += v0.z; a0.w += v0.w;
        a1.x += v1.x; a1.y += v1.y; a1.z += v1.z; a1.w += v1.w;
    }
    float sc = 1.f / (float)(n > 1 ? n : 1);
    a0.x *= sc; a0.y *= sc; a0.z *= sc; a0.w *= sc;
    a1.x *= sc; a1.y *= sc; a1.z *= sc; a1.w *= sc;
    float* outr = clu_mean + (size_t)c * Dd;
    *(float4*)(outr + t * 4) = a0;
    *(float4*)(outr + 1024 + t * 4) = a1;
    float ss = a0.x * a0.x + a0.y * a0.y + a0.z * a0.z + a0.w * a0.w +
               a1.x * a1.x + a1.y * a1.y + a1.z * a1.z + a1.w * a1.w;
    __shared__ float red[256];
    red[t] = ss;
    __syncthreads();
    for (int s2 = 128; s2 > 0; s2 >>= 1) {
        if (t < s2) red[t] += red[t + s2];
        __syncthreads();
    }
    if (t == 0) simm[c] = red[0];
}

// ---------------- per-batch: A (fp32) + x (bf16) ----------------
__global__ __launch_bounds__(256) void k_build_ax(
    const float* __restrict__ feat, const float* __restrict__ clu_mean,
    const int* __restrict__ labels, const int* __restrict__ indexes,
    const int* __restrict__ knn, const float* __restrict__ all_pred,
    float* __restrict__ Abuf, unsigned short* __restrict__ xbuf) {
    int b = blockIdx.x;
    int tid = threadIdx.x;
    __shared__ float smem[64 * 68];
    __shared__ float Gs[64 * 65];
    __shared__ const float* rowp[64];
    __shared__ float wj[64], rn[64];

    if (tid < 64) {
        int j = tid;
        const float* p;
        if (j == 0) p = feat + (size_t)indexes[b] * Dd;
        else        p = clu_mean + (size_t)labels[knn[b * 64 + j]] * Dd;
        rowp[j] = p;
    }

    int ty = tid >> 4, tx = tid & 15;
    float acc[4][4];
#pragma unroll
    for (int i = 0; i < 4; i++)
#pragma unroll
        for (int j = 0; j < 4; j++) acc[i][j] = 0.f;

    for (int ch = 0; ch < 32; ch++) {
        int d0 = ch * 64;
        __syncthreads();
#pragma unroll
        for (int kq = 0; kq < 4; kq++) {
            int e4 = tid + kq * 256;
            int row = e4 >> 4;
            int c4 = (e4 & 15) * 4;
            float4 v = *(const float4*)(rowp[row] + d0 + c4);
            *(float4*)&smem[row * 68 + c4] = v;
        }
        __syncthreads();
        for (int d = 0; d < 64; d += 4) {
            float4 a4[4], b4[4];
#pragma unroll
            for (int i = 0; i < 4; i++) a4[i] = *(const float4*)&smem[(ty * 4 + i) * 68 + d];
#pragma unroll
            for (int j = 0; j < 4; j++) b4[j] = *(const float4*)&smem[(tx * 4 + j) * 68 + d];
#pragma unroll
            for (int i = 0; i < 4; i++) {
#pragma unroll
                for (int j = 0; j < 4; j++) {
                    acc[i][j] += a4[i].x * b4[j].x + a4[i].y * b4[j].y +
                                 a4[i].z * b4[j].z + a4[i].w * b4[j].w;
                }
            }
        }
    }
#pragma unroll
    for (int i = 0; i < 4; i++)
#pragma unroll
        for (int j = 0; j < 4; j++) Gs[(ty * 4 + i) * 65 + tx * 4 + j] = acc[i][j];
    __syncthreads();
    if (tid < 64) {
        rn[tid] = rsqrtf(Gs[tid * 65 + tid]);
        wj[tid] = expf(all_pred[(b * 64 + tid) * 2 + 1]);
    }
    __syncthreads();
    if (tid < 64) {
        int r = tid;
        float mx = -1e30f;
        for (int c = 0; c < 64; c++) {
            float v = Gs[r * 65 + c] * wj[c];
            mx = fmaxf(mx, v);
        }
        float s = 0.f;
        for (int c = 0; c < 64; c++) {
            float e = expf(Gs[r * 65 + c] * wj[c] - mx);
            Gs[r * 65 + c] = e;
            s += e;
        }
        float inv = 1.f / s;
        float* Arow = Abuf + ((size_t)b * 64 + r) * 64;
        for (int c = 0; c < 64; c++) Arow[c] = Gs[r * 65 + c] * inv;
    }
    __syncthreads();
    float rn0 = rn[0];
    const float* piv = rowp[0];
    for (int c4 = tid; c4 < 512; c4 += 256) {
        float4 v = *(const float4*)(piv + c4 * 4);
        v.x *= rn0; v.y *= rn0; v.z *= rn0; v.w *= rn0;
        *(float4*)&smem[c4 * 4] = v;
    }
    __syncthreads();
    unsigned short* xo = xbuf + (size_t)b * 64 * Dd;
    for (int e4 = tid; e4 < 64 * 512; e4 += 256) {
        int row = e4 >> 9;
        int c4 = (e4 & 511) * 4;
        float4 v = *(const float4*)(rowp[row] + c4);
        float r_ = rn[row];
        float4 p = *(const float4*)&smem[c4];
        ushort4 o_;
        o_.x = f2bf(v.x * r_ - p.x);
        o_.y = f2bf(v.y * r_ - p.y);
        o_.z = f2bf(v.z * r_ - p.z);
        o_.w = f2bf(v.w * r_ - p.w);
        *(ushort4*)&xo[row * Dd + c4] = o_;
    }
}

// ---------------- weight repack: f32 [rows,Nhalf] -> Bp[k/8][Ntot][8] bf16 ----------------
// SPLIT=1: W is [2K, Nhalf] (L-GCN cat weight); n<Nhalf -> W[k][n], else W[K+k][n-Nhalf]
// SPLIT=0: W is [K, Nhalf], Ntot=Nhalf
template <int SPLIT>
__global__ __launch_bounds__(256) void k_pack_w(const float* __restrict__ W,
                                                unsigned short* __restrict__ Bp,
                                                int K, int Nhalf) {
    int Ntot = SPLIT ? 2 * Nhalf : Nhalf;
    int idx = blockIdx.x * 256 + threadIdx.x;   // [0, K/8 * Ntot)
    int kb = idx / Ntot;
    int n = idx - kb * Ntot;
    ushort4 lo, hi;
    float v[8];
#pragma unroll
    for (int j = 0; j < 8; j++) {
        int k = kb * 8 + j;
        if (SPLIT)
            v[j] = (n < Nhalf) ? W[(size_t)k * Nhalf + n]
                               : W[(size_t)(K + k) * Nhalf + (n - Nhalf)];
        else
            v[j] = W[(size_t)k * Nhalf + n];
    }
    lo.x = f2bf(v[0]); lo.y = f2bf(v[1]); lo.z = f2bf(v[2]); lo.w = f2bf(v[3]);
    hi.x = f2bf(v[4]); hi.y = f2bf(v[5]); hi.z = f2bf(v[6]); hi.w = f2bf(v[7]);
    *(ushort4*)&Bp[(size_t)idx * 8] = lo;
    *(ushort4*)&Bp[(size_t)idx * 8 + 4] = hi;
}

// ---------------- bf16 MFMA GEMM: C[M,N] = A[M,K] @ Bp (m97 structure) ----------------
// A bf16 row-major (lda=K); Bp packed [K/8][N][8] bf16; C fp32 row-major (ldc=N)
// EPI 0: plain store; EPI 1: bias + PReLU
template <int EPI>
__global__ __launch_bounds__(256) void gemm_bf16_mfma(
    const unsigned short* __restrict__ A, const unsigned short* __restrict__ Bp,
    float* __restrict__ C, int M, int K, int N,
    const float* __restrict__ bias, const float* __restrict__ pre_a) {
    __shared__ unsigned short Asm[128 * 32];    // [row][32] bf16, 8 KB
    __shared__ unsigned short Bsm[4 * 128 * 8]; // [quad][n][8], 8 KB
    int tid = threadIdx.x;
    int wave = tid >> 6, lane = tid & 63;
    int quad = lane >> 4, l16 = lane & 15;
    int m0 = blockIdx.y * 128, n0 = blockIdx.x * 128;
    int wm = (wave >> 1) * 64, wn = (wave & 1) * 64;

    f32x4 acc[4][4];
#pragma unroll
    for (int i = 0; i < 4; i++)
#pragma unroll
        for (int j = 0; j < 4; j++) acc[i][j] = (f32x4){0.f, 0.f, 0.f, 0.f};

    int ia0 = wave * 2, ia1 = wave * 2 + 1;
    const unsigned short* gA0 = A + (size_t)(m0 + ia0 * 16 + (lane >> 2)) * K + (lane & 3) * 8;
    const unsigned short* gA1 = gA0 + (size_t)16 * K;
    const unsigned short* gB0 = Bp + (size_t)(n0 + lane) * 8 + (size_t)wave * N * 8;

    for (int k0 = 0; k0 < K; k0 += 32) {
        __syncthreads();
        size_t bko = (size_t)(k0 >> 3) * N * 8;
        __builtin_amdgcn_global_load_lds(
            (const __attribute__((address_space(1))) void*)(gA0 + k0),
            (__attribute__((address_space(3))) void*)(Asm + ia0 * 512), 16, 0, 0);
        __builtin_amdgcn_global_load_lds(
            (const __attribute__((address_space(1))) void*)(gA1 + k0),
            (__attribute__((address_space(3))) void*)(Asm + ia1 * 512), 16, 0, 0);
        __builtin_amdgcn_global_load_lds(
            (const __attribute__((address_space(1))) void*)(gB0 + bko),
            (__attribute__((address_space(3))) void*)(Bsm + wave * 1024), 16, 0, 0);
        __builtin_amdgcn_global_load_lds(
            (const __attribute__((address_space(1))) void*)(gB0 + bko + 512),
            (__attribute__((address_space(3))) void*)(Bsm + wave * 1024 + 512), 16, 0, 0);
        __syncthreads();

        bf16x8 a[4], b[4];
#pragma unroll
        for (int i = 0; i < 4; i++)
            a[i] = *(const bf16x8*)&Asm[(wm + i * 16 + l16) * 32 + quad * 8];
#pragma unroll
        for (int j = 0; j < 4; j++)
            b[j] = *(const bf16x8*)&Bsm[quad * 1024 + (wn + j * 16 + l16) * 8];
#pragma unroll
        for (int i = 0; i < 4; i++)
#pragma unroll
            for (int j = 0; j < 4; j++)
                acc[i][j] = __builtin_amdgcn_mfma_f32_16x16x32_bf16(
                    a[i], b[j], acc[i][j], 0, 0, 0);
    }

#pragma unroll
    for (int i = 0; i < 4; i++) {
#pragma unroll
        for (int j = 0; j < 4; j++) {
            int col = n0 + wn + j * 16 + l16;
            float bcol = (EPI == 1) ? bias[col] : 0.f;
            float acol = (EPI == 1) ? pre_a[col] : 0.f;
#pragma unroll
            for (int r = 0; r < 4; r++) {
                int row = m0 + wm + i * 16 + quad * 4 + r;
                float v = acc[i][j][r];
                if (EPI == 1) {
                    v += bcol;
                    v = (v >= 0.f) ? v : acol * v;
                }
                C[(size_t)row * N + col] = v;
            }
        }
    }
}

// ---------------- per-batch mixing: out = relu(Ua + A@Ub + bias) ----------------
// OBF=1: output bf16; OBF=0: output fp32
template <int OBF>
__global__ __launch_bounds__(256) void k_layer_agg(
    const float* __restrict__ Uab, const float* __restrict__ Abuf,
    const float* __restrict__ bias, void* __restrict__ outp, int Nc) {
    int b = blockIdx.x;
    int tid = threadIdx.x;
    __shared__ float Ast[64 * 68];
    __shared__ float Us[64 * 68];
    int ty = tid >> 4, tx = tid & 15;
    const float* Ab = Abuf + (size_t)b * 64 * 64;
    for (int e4 = tid; e4 < 1024; e4 += 256) {
        float4 v = *(const float4*)(Ab + e4 * 4);
        int row = e4 >> 4;
        int c4 = (e4 & 15) * 4;
        Ast[(c4 + 0) * 68 + row] = v.x;
        Ast[(c4 + 1) * 68 + row] = v.y;
        Ast[(c4 + 2) * 68 + row] = v.z;
        Ast[(c4 + 3) * 68 + row] = v.w;
    }
    int ldU = 2 * Nc;
    const float* Ua = Uab;
    const float* Ub = Uab + Nc;
    for (int n0 = 0; n0 < Nc; n0 += 64) {
        __syncthreads();
#pragma unroll
        for (int kq = 0; kq < 4; kq++) {
            int e4 = tid + kq * 256;
            int row = e4 >> 4;
            int c4 = (e4 & 15) * 4;
            float4 v = *(const float4*)(Ub + (size_t)(b * 64 + row) * ldU + n0 + c4);
            *(float4*)&Us[row * 68 + c4] = v;
        }
        __syncthreads();
        float acc[4][4];
#pragma unroll
        for (int i = 0; i < 4; i++)
#pragma unroll
            for (int j = 0; j < 4; j++) acc[i][j] = 0.f;
        for (int kk = 0; kk < 64; kk++) {
            float4 a4 = *(const float4*)&Ast[kk * 68 + ty * 4];
            float4 b4 = *(const float4*)&Us[kk * 68 + tx * 4];
            float aa[4] = {a4.x, a4.y, a4.z, a4.w};
            float bb[4] = {b4.x, b4.y, b4.z, b4.w};
#pragma unroll
            for (int i = 0; i < 4; i++)
#pragma unroll
                for (int j = 0; j < 4; j++) acc[i][j] += aa[i] * bb[j];
        }
#pragma unroll
        for (int i = 0; i < 4; i++) {
            int m = b * 64 + ty * 4 + i;
            int n = n0 + tx * 4;
            float4 ua = *(const float4*)(Ua + (size_t)m * ldU + n);
            float v0 = fmaxf(ua.x + acc[i][0] + bias[n + 0], 0.f);
            float v1 = fmaxf(ua.y + acc[i][1] + bias[n + 1], 0.f);
            float v2 = fmaxf(ua.z + acc[i][2] + bias[n + 2], 0.f);
            float v3 = fmaxf(ua.w + acc[i][3] + bias[n + 3], 0.f);
            if (OBF) {
                ushort4 o_;
                o_.x = f2bf(v0); o_.y = f2bf(v1); o_.z = f2bf(v2); o_.w = f2bf(v3);
                *(ushort4*)((unsigned short*)outp + (size_t)m * Nc + n) = o_;
            } else {
                float4 o_ = {v0, v1, v2, v3};
                *(float4*)((float*)outp + (size_t)m * Nc + n) = o_;
            }
        }
        __syncthreads();
    }
}

// ---------------- logits + 2-class softmax ----------------
__global__ __launch_bounds__(256) void k_logits(
    const float* __restrict__ h, const float* __restrict__ Wc2,
    const float* __restrict__ bc2, float* __restrict__ pred) {
    __shared__ float p0[256], p1[256];
    int tid = threadIdx.x;
    int r = tid >> 2, s = tid & 3;
    int m = blockIdx.x * 64 + r;
    const float* hr = h + (size_t)m * 256;
    float l0 = 0.f, l1 = 0.f;
    for (int k = s; k < 256; k += 4) {
        float hv = hr[k];
        l0 += hv * Wc2[2 * k];
        l1 += hv * Wc2[2 * k + 1];
    }
    p0[tid] = l0;
    p1[tid] = l1;
    __syncthreads();
    if (s == 0) {
        float L0 = p0[tid] + p0[tid + 1] + p0[tid + 2] + p0[tid + 3] + bc2[0];
        float L1 = p1[tid] + p1[tid + 1] + p1[tid + 2] + p1[tid + 3] + bc2[1];
        float mx = fmaxf(L0, L1);
        float e0 = expf(L0 - mx), e1 = expf(L1 - mx);
        float inv = 1.f / (e0 + e1);
        pred[2 * m] = e0 * inv;
        pred[2 * m + 1] = e1 * inv;
    }
}

// ---------------- launch ----------------
extern "C" void kernel_launch(void* const* d_in, const int* in_sizes, int n_in,
                              void* d_out, int out_size, void* d_ws, size_t ws_size,
                              hipStream_t stream) {
    const int* indexes = (const int*)d_in[0];
    const float* features = (const float*)d_in[1];
    const int* labels = (const int*)d_in[2];
    const int* knn = (const int*)d_in[5];
    const float* all_pred = (const float*)d_in[6];
    const float* W1 = (const float*)d_in[7];
    const float* b1 = (const float*)d_in[8];
    const float* W2 = (const float*)d_in[9];
    const float* b2 = (const float*)d_in[10];
    const float* Wc1 = (const float*)d_in[11];
    const float* bc1 = (const float*)d_in[12];
    const float* pre_a = (const float*)d_in[13];
    const float* Wc2 = (const float*)d_in[14];
    const float* bc2 = (const float*)d_in[15];
    float* out = (float*)d_out;

    char* w = (char*)d_ws;
    size_t o = 0;
    auto carve = [&](size_t bytes) -> char* {
        char* p = w + o;
        o += (bytes + 255) & ~(size_t)255;
        return p;
    };
    int* cnt = (int*)carve((size_t)Cc * 4);
    int* off = (int*)carve((size_t)Cc * 4);
    int* pos = (int*)carve((size_t)Cc * 4);
    int* rowidx = (int*)carve((size_t)Nn * 4);
    float* clu_mean = (float*)carve((size_t)Cc * Dd * 4);                       // 41 MB
    unsigned short* xbuf = (unsigned short*)carve((size_t)Bq * Kn * Dd * 2);    // 67 MB
    float* Abuf = (float*)carve((size_t)Bq * Kn * Kn * 4);                      // 4.2 MB
    float* U = (float*)carve((size_t)Bq * Kn * 2 * NHID * 4);                   // 67 MB
    unsigned short* Bp1 = (unsigned short*)carve((size_t)(Dd / 8) * 1024 * 8 * 2);   // 4.2 MB
    unsigned short* x1 = (unsigned short*)carve((size_t)Bq * Kn * NHID * 2);    // 16.8 MB
    float* V = (float*)carve((size_t)Bq * Kn * 2 * H2d * 4);                    // 33.6 MB
    unsigned short* Bp2 = (unsigned short*)carve((size_t)(NHID / 8) * 512 * 8 * 2);  // 0.52 MB
    unsigned short* x2 = (unsigned short*)carve((size_t)Bq * Kn * H2d * 2);     // 8.4 MB
    float* h = (float*)carve((size_t)Bq * Kn * H2d * 4);                        // 16.8 MB
    unsigned short* Bpc = (unsigned short*)carve((size_t)(H2d / 8) * 256 * 8 * 2);   // 0.13 MB

    float* simm_out = out + (size_t)Bq * Kn * 2;

    // 1) cluster bucketing
    k_zero_int<<<(Cc + 255) / 256, 256, 0, stream>>>(cnt, Cc);
    k_count<<<(Nn + 255) / 256, 256, 0, stream>>>(labels, cnt, Nn);
    k_scan<<<1, 1024, 0, stream>>>(cnt, off, pos, Cc);
    k_scatter<<<(Nn + 255) / 256, 256, 0, stream>>>(labels, pos, rowidx, Nn);

    // 2) cluster means + simm output
    k_meansimm<<<Cc, 256, 0, stream>>>(features, rowidx, off, cnt, clu_mean, simm_out);

    // 3) per-batch adjacency + normalized/centered x (bf16)
    k_build_ax<<<Bq, 256, 0, stream>>>(features, clu_mean, labels, indexes, knn,
                                       all_pred, Abuf, xbuf);

    // 3b) weight packs (bf16 MFMA-native)
    k_pack_w<1><<<(Dd / 8) * 1024 / 256, 256, 0, stream>>>(W1, Bp1, Dd, NHID);
    k_pack_w<1><<<(NHID / 8) * 512 / 256, 256, 0, stream>>>(W2, Bp2, NHID, H2d);
    k_pack_w<0><<<(H2d / 8) * 256 / 256, 256, 0, stream>>>(Wc1, Bpc, H2d, H2d);

    // 4) U = [x @ W1a | x @ W1b]  (M=16384, K=2048, N=1024)
    {
        dim3 g(1024 / 128, (Bq * Kn) / 128);
        gemm_bf16_mfma<0><<<g, 256, 0, stream>>>(xbuf, Bp1, U, Bq * Kn, Dd, 1024,
                                                 nullptr, nullptr);
    }
    // 5) x1 = relu(Ua + A@Ub + b1)  -> bf16
    k_layer_agg<1><<<Bq, 256, 0, stream>>>(U, Abuf, b1, x1, NHID);

    // 6) V = [x1 @ W2a | x1 @ W2b]  (M=16384, K=512, N=512)
    {
        dim3 g(512 / 128, (Bq * Kn) / 128);
        gemm_bf16_mfma<0><<<g, 256, 0, stream>>>(x1, Bp2, V, Bq * Kn, NHID, 512,
                                                 nullptr, nullptr);
    }
    // 7) x2 = relu(Va + A@Vb + b2)  -> bf16
    k_layer_agg<1><<<Bq, 256, 0, stream>>>(V, Abuf, b2, x2, H2d);

    // 8) h = prelu(x2 @ Wc1 + bc1)  (M=16384, K=256, N=256, fused epilogue)
    {
        dim3 g(256 / 128, (Bq * Kn) / 128);
        gemm_bf16_mfma<1><<<g, 256, 0, stream>>>(x2, Bpc, h, Bq * Kn, H2d, 256,
                                                 bc1, pre_a);
    }
    // 9) logits + softmax -> pred
    k_logits<<<(Bq * Kn) / 64, 256, 0, stream>>>(h, Wc2, bc2, out);

    (void)in_sizes; (void)n_in; (void)out_size; (void)ws_size;
}

// Round 4
// 904.369 us; speedup vs baseline: 2.1675x; 1.0957x over previous
//
#include <hip/hip_runtime.h>
#include <math.h>

#define Bq 256
#define Kn 64
#define Dd 2048
#define Nn 50000
#define Cc 5000
#define NHID 512
#define H2d 256
#define LDH 264   // padded LDS row stride (shorts) for gram staging

typedef __attribute__((ext_vector_type(8))) __bf16 bf16x8;
typedef __attribute__((ext_vector_type(4))) float f32x4;

__device__ __forceinline__ unsigned short f2bf(float f) {
    union { float f; unsigned int u; } v;
    v.f = f;
    unsigned int u = v.u;
    unsigned int r = (u + 0x7fff + ((u >> 16) & 1)) >> 16;   // RNE
    return (unsigned short)r;
}
__device__ __forceinline__ float bf2f(unsigned short h) {
    union { unsigned int u; float f; } v;
    v.u = ((unsigned int)h) << 16;
    return v.f;
}

// ---------------- small utility kernels ----------------

__global__ void k_zero_int(int* __restrict__ p, int n) {
    int i = blockIdx.x * 256 + threadIdx.x;
    if (i < n) p[i] = 0;
}

__global__ void k_count(const int* __restrict__ labels, int* __restrict__ cnt, int n) {
    int i = blockIdx.x * 256 + threadIdx.x;
    if (i < n) atomicAdd(&cnt[labels[i]], 1);
}

__global__ __launch_bounds__(1024) void k_scan(const int* __restrict__ cnt,
                                               int* __restrict__ off,
                                               int* __restrict__ pos, int C) {
    __shared__ int s[1024];
    __shared__ int carry;
    int tid = threadIdx.x;
    if (tid == 0) carry = 0;
    __syncthreads();
    for (int base = 0; base < C; base += 1024) {
        int i = base + tid;
        int v = (i < C) ? cnt[i] : 0;
        s[tid] = v;
        __syncthreads();
        for (int o = 1; o < 1024; o <<= 1) {
            int t = (tid >= o) ? s[tid - o] : 0;
            __syncthreads();
            s[tid] += t;
            __syncthreads();
        }
        int excl = carry + s[tid] - v;
        if (i < C) { off[i] = excl; pos[i] = excl; }
        __syncthreads();
        if (tid == 0) carry += s[1023];
        __syncthreads();
    }
}

__global__ void k_scatter(const int* __restrict__ labels, int* __restrict__ pos,
                          int* __restrict__ rowidx, int n) {
    int i = blockIdx.x * 256 + threadIdx.x;
    if (i < n) {
        int p = atomicAdd(&pos[labels[i]], 1);
        rowidx[p] = i;
    }
}

// ---------------- cluster mean + simm (float4 loads) ----------------
__global__ __launch_bounds__(256) void k_meansimm(
    const float* __restrict__ feat, const int* __restrict__ rowidx,
    const int* __restrict__ off, const int* __restrict__ cnt,
    float* __restrict__ clu_mean, float* __restrict__ simm) {
    int c = blockIdx.x;
    int t = threadIdx.x;
    int n = cnt[c], st = off[c];
    float4 a0 = {0.f, 0.f, 0.f, 0.f}, a1 = {0.f, 0.f, 0.f, 0.f};
    for (int r = 0; r < n; r++) {
        const float* row = feat + (size_t)rowidx[st + r] * Dd;
        float4 v0 = *(const float4*)(row + t * 4);
        float4 v1 = *(const float4*)(row + 1024 + t * 4);
        a0.x += v0.x; a0.y += v0.y; a0.z += v0.z; a0.w += v0.w;
        a1.x += v1.x; a1.y += v1.y; a1.z += v1.z; a1.w += v1.w;
    }
    float sc = 1.f / (float)(n > 1 ? n : 1);
    a0.x *= sc; a0.y *= sc; a0.z *= sc; a0.w *= sc;
    a1.x *= sc; a1.y *= sc; a1.z *= sc; a1.w *= sc;
    float* outr = clu_mean + (size_t)c * Dd;
    *(float4*)(outr + t * 4) = a0;
    *(float4*)(outr + 1024 + t * 4) = a1;
    float ss = a0.x * a0.x + a0.y * a0.y + a0.z * a0.z + a0.w * a0.w +
               a1.x * a1.x + a1.y * a1.y + a1.z * a1.z + a1.w * a1.w;
    __shared__ float red[256];
    red[t] = ss;
    __syncthreads();
    for (int s2 = 128; s2 > 0; s2 >>= 1) {
        if (t < s2) red[t] += red[t + s2];
        __syncthreads();
    }
    if (t == 0) simm[c] = red[0];
}

// ---------------- per-batch: A (MFMA hi/lo gram) + x (bf16) ----------------
__global__ __launch_bounds__(256) void k_build_ax(
    const float* __restrict__ feat, const float* __restrict__ clu_mean,
    const int* __restrict__ labels, const int* __restrict__ indexes,
    const int* __restrict__ knn, const float* __restrict__ all_pred,
    float* __restrict__ Abuf, unsigned short* __restrict__ xbuf) {
    __shared__ unsigned short Hs[64 * LDH];   // hi bf16, padded rows (33 KB)
    __shared__ unsigned short Ls[64 * LDH];   // lo bf16 (33 KB)
    __shared__ float Gs[64 * 65];
    __shared__ const float* rowp[64];
    __shared__ float wj64[64], rn[64];
    __shared__ float piv[2048];

    int b = blockIdx.x, tid = threadIdx.x;
    int wave = tid >> 6, lane = tid & 63, quad = lane >> 4, l16 = lane & 15;

    if (tid < 64) {
        const float* p = (tid == 0) ? feat + (size_t)indexes[b] * Dd
                                    : clu_mean + (size_t)labels[knn[b * 64 + tid]] * Dd;
        rowp[tid] = p;
        wj64[tid] = expf(all_pred[(b * 64 + tid) * 2 + 1]);
    }
    __syncthreads();

    // G = F F^T via 3-pass hi/lo bf16 MFMA, fp32 accumulate.
    // wave w owns the 16-row strip [w*16, w*16+16); 4 col-tiles of 16.
    f32x4 acc[4];
#pragma unroll
    for (int j = 0; j < 4; j++) acc[j] = (f32x4){0.f, 0.f, 0.f, 0.f};

    for (int ch = 0; ch < 8; ch++) {
        int d0 = ch * 256;
        __syncthreads();   // protect Hs/Ls from previous chunk's readers
        // stage 64 rows x 256 cols: 4096 float4, 16 per thread; convert to hi/lo
#pragma unroll
        for (int q = 0; q < 16; q++) {
            int e4 = tid + q * 256;
            int row = e4 >> 6;
            int c4 = (e4 & 63) * 4;
            float4 v = *(const float4*)(rowp[row] + d0 + c4);
            ushort4 h, l;
            h.x = f2bf(v.x); l.x = f2bf(v.x - bf2f(h.x));
            h.y = f2bf(v.y); l.y = f2bf(v.y - bf2f(h.y));
            h.z = f2bf(v.z); l.z = f2bf(v.z - bf2f(h.z));
            h.w = f2bf(v.w); l.w = f2bf(v.w - bf2f(h.w));
            *(ushort4*)&Hs[row * LDH + c4] = h;
            *(ushort4*)&Ls[row * LDH + c4] = l;
        }
        __syncthreads();
#pragma unroll
        for (int ks = 0; ks < 8; ks++) {
            int kk = ks * 32 + quad * 8;
            bf16x8 ah = *(const bf16x8*)&Hs[(wave * 16 + l16) * LDH + kk];
            bf16x8 al = *(const bf16x8*)&Ls[(wave * 16 + l16) * LDH + kk];
#pragma unroll
            for (int j = 0; j < 4; j++) {
                bf16x8 bh = *(const bf16x8*)&Hs[(j * 16 + l16) * LDH + kk];
                bf16x8 bl = *(const bf16x8*)&Ls[(j * 16 + l16) * LDH + kk];
                acc[j] = __builtin_amdgcn_mfma_f32_16x16x32_bf16(ah, bh, acc[j], 0, 0, 0);
                acc[j] = __builtin_amdgcn_mfma_f32_16x16x32_bf16(ah, bl, acc[j], 0, 0, 0);
                acc[j] = __builtin_amdgcn_mfma_f32_16x16x32_bf16(al, bh, acc[j], 0, 0, 0);
            }
        }
    }
    __syncthreads();
    // C/D layout: col = l16, row = quad*4 + r
#pragma unroll
    for (int j = 0; j < 4; j++)
#pragma unroll
        for (int r = 0; r < 4; r++)
            Gs[(wave * 16 + quad * 4 + r) * 65 + j * 16 + l16] = acc[j][r];
    __syncthreads();
    if (tid < 64) rn[tid] = rsqrtf(Gs[tid * 65 + tid]);
    __syncthreads();
    // row softmax (thread r handles row r)
    if (tid < 64) {
        int r = tid;
        float mx = -1e30f;
        for (int c = 0; c < 64; c++) {
            float v = Gs[r * 65 + c] * wj64[c];
            mx = fmaxf(mx, v);
        }
        float s = 0.f;
        for (int c = 0; c < 64; c++) {
            float e = expf(Gs[r * 65 + c] * wj64[c] - mx);
            Gs[r * 65 + c] = e;
            s += e;
        }
        float inv = 1.f / s;
        float* Arow = Abuf + ((size_t)b * 64 + r) * 64;
        for (int c = 0; c < 64; c++) Arow[c] = Gs[r * 65 + c] * inv;
    }
    __syncthreads();
    // pivot * rn0 into piv[]
    float rn0 = rn[0];
    const float* pivp = rowp[0];
    for (int c4 = tid; c4 < 512; c4 += 256) {
        float4 v = *(const float4*)(pivp + c4 * 4);
        v.x *= rn0; v.y *= rn0; v.z *= rn0; v.w *= rn0;
        *(float4*)&piv[c4 * 4] = v;
    }
    __syncthreads();
    // x = normalize(F) - piv, bf16 out
    unsigned short* xo = xbuf + (size_t)b * 64 * Dd;
    for (int e4 = tid; e4 < 64 * 512; e4 += 256) {
        int row = e4 >> 9;
        int c4 = (e4 & 511) * 4;
        float4 v = *(const float4*)(rowp[row] + c4);
        float r_ = rn[row];
        float4 p = *(const float4*)&piv[c4];
        ushort4 o_;
        o_.x = f2bf(v.x * r_ - p.x);
        o_.y = f2bf(v.y * r_ - p.y);
        o_.z = f2bf(v.z * r_ - p.z);
        o_.w = f2bf(v.w * r_ - p.w);
        *(ushort4*)&xo[row * Dd + c4] = o_;
    }
}

// ---------------- weight repack: f32 [rows,Nhalf] -> Bp[k/8][Ntot][8] bf16 ----------------
template <int SPLIT>
__global__ __launch_bounds__(256) void k_pack_w(const float* __restrict__ W,
                                                unsigned short* __restrict__ Bp,
                                                int K, int Nhalf) {
    int Ntot = SPLIT ? 2 * Nhalf : Nhalf;
    int idx = blockIdx.x * 256 + threadIdx.x;
    int kb = idx / Ntot;
    int n = idx - kb * Ntot;
    ushort4 lo, hi;
    float v[8];
#pragma unroll
    for (int j = 0; j < 8; j++) {
        int k = kb * 8 + j;
        if (SPLIT)
            v[j] = (n < Nhalf) ? W[(size_t)k * Nhalf + n]
                               : W[(size_t)(K + k) * Nhalf + (n - Nhalf)];
        else
            v[j] = W[(size_t)k * Nhalf + n];
    }
    lo.x = f2bf(v[0]); lo.y = f2bf(v[1]); lo.z = f2bf(v[2]); lo.w = f2bf(v[3]);
    hi.x = f2bf(v[4]); hi.y = f2bf(v[5]); hi.z = f2bf(v[6]); hi.w = f2bf(v[7]);
    *(ushort4*)&Bp[(size_t)idx * 8] = lo;
    *(ushort4*)&Bp[(size_t)idx * 8 + 4] = hi;
}

// ---------------- bf16 MFMA GEMM (m97 structure) ----------------
template <int EPI>
__global__ __launch_bounds__(256) void gemm_bf16_mfma(
    const unsigned short* __restrict__ A, const unsigned short* __restrict__ Bp,
    float* __restrict__ C, int M, int K, int N,
    const float* __restrict__ bias, const float* __restrict__ pre_a) {
    __shared__ unsigned short Asm[128 * 32];
    __shared__ unsigned short Bsm[4 * 128 * 8];
    int tid = threadIdx.x;
    int wave = tid >> 6, lane = tid & 63;
    int quad = lane >> 4, l16 = lane & 15;
    int m0 = blockIdx.y * 128, n0 = blockIdx.x * 128;
    int wm = (wave >> 1) * 64, wn = (wave & 1) * 64;

    f32x4 acc[4][4];
#pragma unroll
    for (int i = 0; i < 4; i++)
#pragma unroll
        for (int j = 0; j < 4; j++) acc[i][j] = (f32x4){0.f, 0.f, 0.f, 0.f};

    int ia0 = wave * 2, ia1 = wave * 2 + 1;
    const unsigned short* gA0 = A + (size_t)(m0 + ia0 * 16 + (lane >> 2)) * K + (lane & 3) * 8;
    const unsigned short* gA1 = gA0 + (size_t)16 * K;
    const unsigned short* gB0 = Bp + (size_t)(n0 + lane) * 8 + (size_t)wave * N * 8;

    for (int k0 = 0; k0 < K; k0 += 32) {
        __syncthreads();
        size_t bko = (size_t)(k0 >> 3) * N * 8;
        __builtin_amdgcn_global_load_lds(
            (const __attribute__((address_space(1))) void*)(gA0 + k0),
            (__attribute__((address_space(3))) void*)(Asm + ia0 * 512), 16, 0, 0);
        __builtin_amdgcn_global_load_lds(
            (const __attribute__((address_space(1))) void*)(gA1 + k0),
            (__attribute__((address_space(3))) void*)(Asm + ia1 * 512), 16, 0, 0);
        __builtin_amdgcn_global_load_lds(
            (const __attribute__((address_space(1))) void*)(gB0 + bko),
            (__attribute__((address_space(3))) void*)(Bsm + wave * 1024), 16, 0, 0);
        __builtin_amdgcn_global_load_lds(
            (const __attribute__((address_space(1))) void*)(gB0 + bko + 512),
            (__attribute__((address_space(3))) void*)(Bsm + wave * 1024 + 512), 16, 0, 0);
        __syncthreads();

        bf16x8 a[4], b[4];
#pragma unroll
        for (int i = 0; i < 4; i++)
            a[i] = *(const bf16x8*)&Asm[(wm + i * 16 + l16) * 32 + quad * 8];
#pragma unroll
        for (int j = 0; j < 4; j++)
            b[j] = *(const bf16x8*)&Bsm[quad * 1024 + (wn + j * 16 + l16) * 8];
#pragma unroll
        for (int i = 0; i < 4; i++)
#pragma unroll
            for (int j = 0; j < 4; j++)
                acc[i][j] = __builtin_amdgcn_mfma_f32_16x16x32_bf16(
                    a[i], b[j], acc[i][j], 0, 0, 0);
    }

#pragma unroll
    for (int i = 0; i < 4; i++) {
#pragma unroll
        for (int j = 0; j < 4; j++) {
            int col = n0 + wn + j * 16 + l16;
            float bcol = (EPI == 1) ? bias[col] : 0.f;
            float acol = (EPI == 1) ? pre_a[col] : 0.f;
#pragma unroll
            for (int r = 0; r < 4; r++) {
                int row = m0 + wm + i * 16 + quad * 4 + r;
                float v = acc[i][j][r];
                if (EPI == 1) {
                    v += bcol;
                    v = (v >= 0.f) ? v : acol * v;
                }
                C[(size_t)row * N + col] = v;
            }
        }
    }
}

// ---------------- per-batch mixing: out = relu(Ua + A@Ub + bias) ----------------
template <int OBF>
__global__ __launch_bounds__(256) void k_layer_agg(
    const float* __restrict__ Uab, const float* __restrict__ Abuf,
    const float* __restrict__ bias, void* __restrict__ outp, int Nc) {
    int b = blockIdx.x;
    int tid = threadIdx.x;
    __shared__ float Ast[64 * 68];
    __shared__ float Us[64 * 68];
    int ty = tid >> 4, tx = tid & 15;
    const float* Ab = Abuf + (size_t)b * 64 * 64;
    for (int e4 = tid; e4 < 1024; e4 += 256) {
        float4 v = *(const float4*)(Ab + e4 * 4);
        int row = e4 >> 4;
        int c4 = (e4 & 15) * 4;
        Ast[(c4 + 0) * 68 + row] = v.x;
        Ast[(c4 + 1) * 68 + row] = v.y;
        Ast[(c4 + 2) * 68 + row] = v.z;
        Ast[(c4 + 3) * 68 + row] = v.w;
    }
    int ldU = 2 * Nc;
    const float* Ua = Uab;
    const float* Ub = Uab + Nc;
    for (int n0 = 0; n0 < Nc; n0 += 64) {
        __syncthreads();
#pragma unroll
        for (int kq = 0; kq < 4; kq++) {
            int e4 = tid + kq * 256;
            int row = e4 >> 4;
            int c4 = (e4 & 15) * 4;
            float4 v = *(const float4*)(Ub + (size_t)(b * 64 + row) * ldU + n0 + c4);
            *(float4*)&Us[row * 68 + c4] = v;
        }
        __syncthreads();
        float acc[4][4];
#pragma unroll
        for (int i = 0; i < 4; i++)
#pragma unroll
            for (int j = 0; j < 4; j++) acc[i][j] = 0.f;
        for (int kk = 0; kk < 64; kk++) {
            float4 a4 = *(const float4*)&Ast[kk * 68 + ty * 4];
            float4 b4 = *(const float4*)&Us[kk * 68 + tx * 4];
            float aa[4] = {a4.x, a4.y, a4.z, a4.w};
            float bb[4] = {b4.x, b4.y, b4.z, b4.w};
#pragma unroll
            for (int i = 0; i < 4; i++)
#pragma unroll
                for (int j = 0; j < 4; j++) acc[i][j] += aa[i] * bb[j];
        }
#pragma unroll
        for (int i = 0; i < 4; i++) {
            int m = b * 64 + ty * 4 + i;
            int n = n0 + tx * 4;
            float4 ua = *(const float4*)(Ua + (size_t)m * ldU + n);
            float v0 = fmaxf(ua.x + acc[i][0] + bias[n + 0], 0.f);
            float v1 = fmaxf(ua.y + acc[i][1] + bias[n + 1], 0.f);
            float v2 = fmaxf(ua.z + acc[i][2] + bias[n + 2], 0.f);
            float v3 = fmaxf(ua.w + acc[i][3] + bias[n + 3], 0.f);
            if (OBF) {
                ushort4 o_;
                o_.x = f2bf(v0); o_.y = f2bf(v1); o_.z = f2bf(v2); o_.w = f2bf(v3);
                *(ushort4*)((unsigned short*)outp + (size_t)m * Nc + n) = o_;
            } else {
                float4 o_ = {v0, v1, v2, v3};
                *(float4*)((float*)outp + (size_t)m * Nc + n) = o_;
            }
        }
        __syncthreads();
    }
}

// ---------------- logits + 2-class softmax ----------------
__global__ __launch_bounds__(256) void k_logits(
    const float* __restrict__ h, const float* __restrict__ Wc2,
    const float* __restrict__ bc2, float* __restrict__ pred) {
    __shared__ float p0[256], p1[256];
    int tid = threadIdx.x;
    int r = tid >> 2, s = tid & 3;
    int m = blockIdx.x * 64 + r;
    const float* hr = h + (size_t)m * 256;
    float l0 = 0.f, l1 = 0.f;
    for (int k = s; k < 256; k += 4) {
        float hv = hr[k];
        l0 += hv * Wc2[2 * k];
        l1 += hv * Wc2[2 * k + 1];
    }
    p0[tid] = l0;
    p1[tid] = l1;
    __syncthreads();
    if (s == 0) {
        float L0 = p0[tid] + p0[tid + 1] + p0[tid + 2] + p0[tid + 3] + bc2[0];
        float L1 = p1[tid] + p1[tid + 1] + p1[tid + 2] + p1[tid + 3] + bc2[1];
        float mx = fmaxf(L0, L1);
        float e0 = expf(L0 - mx), e1 = expf(L1 - mx);
        float inv = 1.f / (e0 + e1);
        pred[2 * m] = e0 * inv;
        pred[2 * m + 1] = e1 * inv;
    }
}

// ---------------- launch ----------------
extern "C" void kernel_launch(void* const* d_in, const int* in_sizes, int n_in,
                              void* d_out, int out_size, void* d_ws, size_t ws_size,
                              hipStream_t stream) {
    const int* indexes = (const int*)d_in[0];
    const float* features = (const float*)d_in[1];
    const int* labels = (const int*)d_in[2];
    const int* knn = (const int*)d_in[5];
    const float* all_pred = (const float*)d_in[6];
    const float* W1 = (const float*)d_in[7];
    const float* b1 = (const float*)d_in[8];
    const float* W2 = (const float*)d_in[9];
    const float* b2 = (const float*)d_in[10];
    const float* Wc1 = (const float*)d_in[11];
    const float* bc1 = (const float*)d_in[12];
    const float* pre_a = (const float*)d_in[13];
    const float* Wc2 = (const float*)d_in[14];
    const float* bc2 = (const float*)d_in[15];
    float* out = (float*)d_out;

    char* w = (char*)d_ws;
    size_t o = 0;
    auto carve = [&](size_t bytes) -> char* {
        char* p = w + o;
        o += (bytes + 255) & ~(size_t)255;
        return p;
    };
    int* cnt = (int*)carve((size_t)Cc * 4);
    int* off = (int*)carve((size_t)Cc * 4);
    int* pos = (int*)carve((size_t)Cc * 4);
    int* rowidx = (int*)carve((size_t)Nn * 4);
    float* clu_mean = (float*)carve((size_t)Cc * Dd * 4);                       // 41 MB
    unsigned short* xbuf = (unsigned short*)carve((size_t)Bq * Kn * Dd * 2);    // 67 MB
    float* Abuf = (float*)carve((size_t)Bq * Kn * Kn * 4);                      // 4.2 MB
    float* U = (float*)carve((size_t)Bq * Kn * 2 * NHID * 4);                   // 67 MB
    unsigned short* Bp1 = (unsigned short*)carve((size_t)(Dd / 8) * 1024 * 8 * 2);   // 4.2 MB
    unsigned short* x1 = (unsigned short*)carve((size_t)Bq * Kn * NHID * 2);    // 16.8 MB
    float* V = (float*)carve((size_t)Bq * Kn * 2 * H2d * 4);                    // 33.6 MB
    unsigned short* Bp2 = (unsigned short*)carve((size_t)(NHID / 8) * 512 * 8 * 2);  // 0.52 MB
    unsigned short* x2 = (unsigned short*)carve((size_t)Bq * Kn * H2d * 2);     // 8.4 MB
    float* h = (float*)carve((size_t)Bq * Kn * H2d * 4);                        // 16.8 MB
    unsigned short* Bpc = (unsigned short*)carve((size_t)(H2d / 8) * 256 * 8 * 2);   // 0.13 MB

    float* simm_out = out + (size_t)Bq * Kn * 2;

    // 1) cluster bucketing
    k_zero_int<<<(Cc + 255) / 256, 256, 0, stream>>>(cnt, Cc);
    k_count<<<(Nn + 255) / 256, 256, 0, stream>>>(labels, cnt, Nn);
    k_scan<<<1, 1024, 0, stream>>>(cnt, off, pos, Cc);
    k_scatter<<<(Nn + 255) / 256, 256, 0, stream>>>(labels, pos, rowidx, Nn);

    // 2) cluster means + simm output
    k_meansimm<<<Cc, 256, 0, stream>>>(features, rowidx, off, cnt, clu_mean, simm_out);

    // 3) per-batch adjacency (MFMA hi/lo gram) + normalized/centered x (bf16)
    k_build_ax<<<Bq, 256, 0, stream>>>(features, clu_mean, labels, indexes, knn,
                                       all_pred, Abuf, xbuf);

    // 3b) weight packs (bf16 MFMA-native)
    k_pack_w<1><<<(Dd / 8) * 1024 / 256, 256, 0, stream>>>(W1, Bp1, Dd, NHID);
    k_pack_w<1><<<(NHID / 8) * 512 / 256, 256, 0, stream>>>(W2, Bp2, NHID, H2d);
    k_pack_w<0><<<(H2d / 8) * 256 / 256, 256, 0, stream>>>(Wc1, Bpc, H2d, H2d);

    // 4) U = [x @ W1a | x @ W1b]  (M=16384, K=2048, N=1024)
    {
        dim3 g(1024 / 128, (Bq * Kn) / 128);
        gemm_bf16_mfma<0><<<g, 256, 0, stream>>>(xbuf, Bp1, U, Bq * Kn, Dd, 1024,
                                                 nullptr, nullptr);
    }
    // 5) x1 = relu(Ua + A@Ub + b1)  -> bf16
    k_layer_agg<1><<<Bq, 256, 0, stream>>>(U, Abuf, b1, x1, NHID);

    // 6) V = [x1 @ W2a | x1 @ W2b]  (M=16384, K=512, N=512)
    {
        dim3 g(512 / 128, (Bq * Kn) / 128);
        gemm_bf16_mfma<0><<<g, 256, 0, stream>>>(x1, Bp2, V, Bq * Kn, NHID, 512,
                                                 nullptr, nullptr);
    }
    // 7) x2 = relu(Va + A@Vb + b2)  -> bf16
    k_layer_agg<1><<<Bq, 256, 0, stream>>>(V, Abuf, b2, x2, H2d);

    // 8) h = prelu(x2 @ Wc1 + bc1)  (M=16384, K=256, N=256, fused epilogue)
    {
        dim3 g(256 / 128, (Bq * Kn) / 128);
        gemm_bf16_mfma<1><<<g, 256, 0, stream>>>(x2, Bpc, h, Bq * Kn, H2d, 256,
                                                 bc1, pre_a);
    }
    // 9) logits + softmax -> pred
    k_logits<<<(Bq * Kn) / 64, 256, 0, stream>>>(h, Wc2, bc2, out);

    (void)in_sizes; (void)n_in; (void)out_size; (void)ws_size;
}